// Round 11
// baseline (230.534 us; speedup 1.0000x reference)
//
#include <hip/hip_runtime.h>
#include <math.h>

typedef short    bf16x8 __attribute__((ext_vector_type(8)));
typedef float    f32x16 __attribute__((ext_vector_type(16)));
typedef float    f32x4  __attribute__((ext_vector_type(4)));
typedef unsigned int u32x4 __attribute__((ext_vector_type(4)));

// element-granular XOR swizzle for the weight tiles (64B-stride rows -> all banks)
#define SWZ(row) ((((row) >> 1) & 3) << 3)

__device__ __forceinline__ unsigned short f2bf(float f) {
    unsigned int u = __builtin_bit_cast(unsigned int, f);
    u = (u + 0x7FFFu + ((u >> 16) & 1u)) >> 16;   // RNE
    return (unsigned short)u;
}
__device__ __forceinline__ unsigned int cvt_pk_bf16(float lo, float hi) {
    unsigned int r;
    asm("v_cvt_pk_bf16_f32 %0, %1, %2" : "=v"(r) : "v"(lo), "v"(hi));
    return r;   // RNE
}
__device__ __forceinline__ float rcp_fast(float x) { return __builtin_amdgcn_rcpf(x); }

// tanh(z) = 1 - 2/(exp(2z)+1) with hardware rcp (1-ulp); saturates correctly.
__device__ __forceinline__ float tanh_f(float z) {
    return fmaf(-2.0f, rcp_fast(__expf(2.0f * z) + 1.0f), 1.0f);
}
__device__ __forceinline__ unsigned int sx32(unsigned int v) {
    return (unsigned int)__shfl_xor((int)v, 32, 64);
}

// Single fused kernel: each block owns 128 points (4 waves x 32) and loops all
// 32 subdomains in chunks of 4 (round-8-verified loop body, ngrp=1, fused epilogue).
// MFMA scheme (swapped operands): D = W^T (A, from LDS) x h^T (B, in regs).
__global__ __launch_bounds__(256) void fbpinn_fused(
    const float* __restrict__ X,
    const float* __restrict__ centers,
    const float* __restrict__ widths,
    const float* __restrict__ core_min,
    const float* __restrict__ core_max,
    const float* __restrict__ overlap,
    const float* __restrict__ W1,
    const float* __restrict__ b1,
    const float* __restrict__ W2,
    const float* __restrict__ b2,
    const float* __restrict__ W3,
    const float* __restrict__ b3,
    const float* __restrict__ Wout,
    const float* __restrict__ bout,
    const float* __restrict__ scale,
    const float* __restrict__ shift,
    float* __restrict__ out,
    int n_pts)
{
    __shared__ __align__(16) unsigned short sW2t[4][1024];  // swizzled [j][k], bf16
    __shared__ __align__(16) unsigned short sW3t[4][1024];
    __shared__ __align__(16) float sW1f[4][64];             // f32 [d][j]
    __shared__ __align__(16) float sB1[4][32], sB2[4][32], sB3[4][32], sWo[4][32];
    __shared__ float sBout[4];

    const int tid  = threadIdx.x;
    const int wave = tid >> 6;
    const int lane = tid & 63;
    const int p    = lane & 31;   // point id within wave; also MFMA D-col
    const int hi   = lane >> 5;   // half selector

    int P = blockIdx.x * 128 + wave * 32 + p;
    if (P >= n_pts) P = n_pts - 1;   // N divides exactly; safety only

    const float t  = X[2 * P + 0];
    const float x  = X[2 * P + 1];
    const float sc = scale[0];
    const float sh = shift[0];

    float num = 0.0f, den = 0.0f;

    // weight-fragment offsets (A-operand = W^T, row = p as neuron, k-slices)
    const int ef0 = (p << 5) + ((hi * 8)      ^ SWZ(p)); // k 0..15 slice
    const int ef1 = (p << 5) + ((16 + hi * 8) ^ SWZ(p)); // k 16..31 slice

    for (int c0 = 0; c0 < 32; c0 += 4) {
        __syncthreads();
        // ---- stage 4 subdomains' weights (bf16 W2/W3, f32 W1 + biases) ----
        {
            const float* W2s = W2 + (size_t)c0 * 1024;
            const float* W3s = W3 + (size_t)c0 * 1024;
            #pragma unroll
            for (int i = 0; i < 16; ++i) {
                int e = tid + (i << 8);            // e = sl*1024 + k*32 + j
                int sl = e >> 10, r = e & 1023;
                int k = r >> 5, j = r & 31;
                int di = (j << 5) + (k ^ SWZ(j));  // transposed + swizzle
                sW2t[sl][di] = f2bf(W2s[e]);
                sW3t[sl][di] = f2bf(W3s[e]);
            }
            sW1f[tid >> 6][tid & 63] = W1[(size_t)c0 * 64 + tid];
            if (tid < 128) {
                int sl = tid >> 5, j = tid & 31;
                int g = (c0 + sl) * 32 + j;
                sB1[sl][j] = b1[g];
                sB2[sl][j] = b2[g];
                sB3[sl][j] = b3[g];
                sWo[sl][j] = Wout[g];
            }
            if (tid < 4) sBout[tid] = bout[c0 + tid];
        }
        __syncthreads();

        for (int si = 0; si < 4; ++si) {
            const int s = c0 + si;

            // ---- window + normalized coords (wave-uniform s_loads) ----
            float wid0 = widths[s * 2 + 0], wid1 = widths[s * 2 + 1];
            float sd0 = 4.0f * rcp_fast(fmaf(2.0f * overlap[s * 2 + 0], wid0, 1e-8f));
            float sd1 = 4.0f * rcp_fast(fmaf(2.0f * overlap[s * 2 + 1], wid1, 1e-8f));
            float z0 = sd0 * (t - core_min[s * 2 + 0]);
            float z1 = sd0 * (core_max[s * 2 + 0] - t);
            float z2 = sd1 * (x - core_min[s * 2 + 1]);
            float z3 = sd1 * (core_max[s * 2 + 1] - x);
            float w = rcp_fast(((1.0f + __expf(-z0)) * (1.0f + __expf(-z1)))
                             * ((1.0f + __expf(-z2)) * (1.0f + __expf(-z3))));
            float xn0 = (t - centers[s * 2 + 0]) * rcp_fast(wid0) + 0.5f;
            float xn1 = (x - centers[s * 2 + 1]) * rcp_fast(wid1) + 0.5f;

            unsigned int pk[8];

            // ---- layer 1 (VALU): lane (p,hi) computes neurons j = 16*hi..+15 ----
            {
                const f32x4* Wa4 = (const f32x4*)&sW1f[si][hi * 16];        // d0
                const f32x4* Wb4 = (const f32x4*)&sW1f[si][32 + hi * 16];   // d1
                const f32x4* Bv4 = (const f32x4*)&sB1[si][hi * 16];
                float Wa[16], Wb[16], Bv[16];
                #pragma unroll
                for (int i = 0; i < 4; ++i) {
                    f32x4 av = Wa4[i], bv = Wb4[i], cv = Bv4[i];
                    #pragma unroll
                    for (int q = 0; q < 4; ++q) {
                        Wa[4 * i + q] = av[q];
                        Wb[4 * i + q] = bv[q];
                        Bv[4 * i + q] = cv[q];
                    }
                }
                #pragma unroll
                for (int q = 0; q < 8; ++q) {
                    float a0 = fmaf(xn0, Wa[2 * q],     fmaf(xn1, Wb[2 * q],     Bv[2 * q]));
                    float a1 = fmaf(xn0, Wa[2 * q + 1], fmaf(xn1, Wb[2 * q + 1], Bv[2 * q + 1]));
                    pk[q] = cvt_pk_bf16(tanh_f(a0), tanh_f(a1));
                }
            }
            // exchange: hi=0 sends j8..15 (pk4..7), hi=1 sends j16..23 (pk0..3)
            bf16x8 Bf0, Bf1;
            {
                unsigned int r0 = sx32(hi ? pk[0] : pk[4]);
                unsigned int r1 = sx32(hi ? pk[1] : pk[5]);
                unsigned int r2 = sx32(hi ? pk[2] : pk[6]);
                unsigned int r3 = sx32(hi ? pk[3] : pk[7]);
                u32x4 f1 = hi ? (u32x4){r0, r1, r2, r3} : (u32x4){pk[0], pk[1], pk[2], pk[3]};
                u32x4 f2 = hi ? (u32x4){pk[4], pk[5], pk[6], pk[7]} : (u32x4){r0, r1, r2, r3};
                Bf0 = __builtin_bit_cast(bf16x8, f1);
                Bf1 = __builtin_bit_cast(bf16x8, f2);
            }

            // ---- layer 2 (MFMA, swapped): D2[j][m] ----
            f32x16 acc;
            {
                bf16x8 A0 = *(bf16x8*)&sW2t[si][ef0];
                bf16x8 A1 = *(bf16x8*)&sW2t[si][ef1];
                #pragma unroll
                for (int i = 0; i < 4; ++i) {
                    f32x4 bv = *(const f32x4*)&sB2[si][8 * i + 4 * hi];
                    #pragma unroll
                    for (int q = 0; q < 4; ++q) acc[4 * i + q] = bv[q];
                }
                acc = __builtin_amdgcn_mfma_f32_32x32x16_bf16(A0, Bf0, acc, 0, 0, 0);
                acc = __builtin_amdgcn_mfma_f32_32x32x16_bf16(A1, Bf1, acc, 0, 0, 0);
            }
            // tanh + pack: pk[q] = neurons (j(2q), j(2q)+1), j(r)=(r&3)+8(r>>2)+4hi
            #pragma unroll
            for (int q = 0; q < 8; ++q)
                pk[q] = cvt_pk_bf16(tanh_f(acc[2 * q]), tanh_f(acc[2 * q + 1]));
            // exchange: hi=0 sends pk2,3 (j8..11) & pk6,7 (j24..27);
            //           hi=1 sends pk0,1 (j4..7)  & pk4,5 (j20..23)
            {
                unsigned int r0 = sx32(hi ? pk[0] : pk[2]);
                unsigned int r1 = sx32(hi ? pk[1] : pk[3]);
                unsigned int r2 = sx32(hi ? pk[4] : pk[6]);
                unsigned int r3 = sx32(hi ? pk[5] : pk[7]);
                u32x4 f1 = hi ? (u32x4){r0, r1, pk[2], pk[3]} : (u32x4){pk[0], pk[1], r0, r1};
                u32x4 f2 = hi ? (u32x4){r2, r3, pk[6], pk[7]} : (u32x4){pk[4], pk[5], r2, r3};
                Bf0 = __builtin_bit_cast(bf16x8, f1);
                Bf1 = __builtin_bit_cast(bf16x8, f2);
            }

            // ---- layer 3 (MFMA, swapped) ----
            {
                bf16x8 A0 = *(bf16x8*)&sW3t[si][ef0];
                bf16x8 A1 = *(bf16x8*)&sW3t[si][ef1];
                #pragma unroll
                for (int i = 0; i < 4; ++i) {
                    f32x4 bv = *(const f32x4*)&sB3[si][8 * i + 4 * hi];
                    #pragma unroll
                    for (int q = 0; q < 4; ++q) acc[4 * i + q] = bv[q];
                }
                acc = __builtin_amdgcn_mfma_f32_32x32x16_bf16(A0, Bf0, acc, 0, 0, 0);
                acc = __builtin_amdgcn_mfma_f32_32x32x16_bf16(A1, Bf1, acc, 0, 0, 0);
            }

            // ---- output dot: y[p] = sum_j tanh(h3[p][j]) * Wout[j] ----
            {
                float yp = 0.0f;
                #pragma unroll
                for (int i = 0; i < 4; ++i) {
                    f32x4 wv = *(const f32x4*)&sWo[si][8 * i + 4 * hi];
                    #pragma unroll
                    for (int q = 0; q < 4; ++q)
                        yp = fmaf(tanh_f(acc[4 * i + q]), wv[q], yp);
                }
                float y = yp + __shfl_xor(yp, 32, 64);   // combine both halves
                y += sBout[si];
                num = fmaf(w, y, num);
                den += w;
            }
        }
    }

    // ---- normalize + scale/shift + ansatz epilogue (fused; num/den identical
    //      on both halves after the shfl combine) ----
    if (hi == 0) {
        // sum w*(sc*y+sh) = sc*sum(w*y) + sh*sum(w)
        float u = fmaf(sc, num, sh * den) / (den + 1e-8f);
        float fac = tanh_f(x + 1.0f) * tanh_f(x - 1.0f) * tanh_f(t);
        const float pi = 3.14159265358979323846f;
        out[P] = fmaf(fac, u, -__sinf(pi * x));
    }
}

extern "C" void kernel_launch(void* const* d_in, const int* in_sizes, int n_in,
                              void* d_out, int out_size, void* d_ws, size_t ws_size,
                              hipStream_t stream) {
    const float* X        = (const float*)d_in[0];
    const float* centers  = (const float*)d_in[1];
    const float* widths   = (const float*)d_in[2];
    const float* core_min = (const float*)d_in[3];
    const float* core_max = (const float*)d_in[4];
    const float* overlap  = (const float*)d_in[5];
    const float* W1       = (const float*)d_in[6];
    const float* b1       = (const float*)d_in[7];
    const float* W2       = (const float*)d_in[8];
    const float* b2       = (const float*)d_in[9];
    const float* W3       = (const float*)d_in[10];
    const float* b3       = (const float*)d_in[11];
    const float* Wout     = (const float*)d_in[12];
    const float* bout     = (const float*)d_in[13];
    const float* scale    = (const float*)d_in[14];
    const float* shift    = (const float*)d_in[15];

    float* out = (float*)d_out;
    const int n_pts = in_sizes[0] / 2;

    const int grid = (n_pts + 127) / 128;   // 128 points per block (4 waves x 32)
    fbpinn_fused<<<grid, 256, 0, stream>>>(
        X, centers, widths, core_min, core_max, overlap,
        W1, b1, W2, b2, W3, b3, Wout, bout, scale, shift,
        out, n_pts);
}

// Round 12
// 207.116 us; speedup vs baseline: 1.1131x; 1.1131x over previous
//
#include <hip/hip_runtime.h>
#include <math.h>

typedef short    bf16x8 __attribute__((ext_vector_type(8)));
typedef float    f32x16 __attribute__((ext_vector_type(16)));
typedef float    f32x4  __attribute__((ext_vector_type(4)));
typedef unsigned int u32x4 __attribute__((ext_vector_type(4)));

// element-granular XOR swizzle for the weight tiles (64B-stride rows -> all banks)
#define SWZ(row) ((((row) >> 1) & 3) << 3)

__device__ __forceinline__ unsigned short f2bf(float f) {
    unsigned int u = __builtin_bit_cast(unsigned int, f);
    u = (u + 0x7FFFu + ((u >> 16) & 1u)) >> 16;   // RNE
    return (unsigned short)u;
}
__device__ __forceinline__ unsigned int cvt_pk_bf16(float lo, float hi) {
    unsigned int r;
    asm("v_cvt_pk_bf16_f32 %0, %1, %2" : "=v"(r) : "v"(lo), "v"(hi));
    return r;   // RNE
}
__device__ __forceinline__ float rcp_fast(float x) { return __builtin_amdgcn_rcpf(x); }

#if __has_builtin(__builtin_amdgcn_exp2f)
__device__ __forceinline__ float exp2_fast(float x) { return __builtin_amdgcn_exp2f(x); }
#else
__device__ __forceinline__ float exp2_fast(float x) {
    float r; asm("v_exp_f32 %0, %1" : "=v"(r) : "v"(x)); return r;
}
#endif

#define TWO_LOG2E 2.8853900817779268f   // 2*log2(e)
#define LOG2E     1.4426950408889634f

// tanh(z) = 1 - 2/(2^(z*2log2e)+1); direct v_exp_f32, saturates correctly.
__device__ __forceinline__ float tanh_f(float z) {
    return fmaf(-2.0f, rcp_fast(exp2_fast(z * TWO_LOG2E) + 1.0f), 1.0f);
}
__device__ __forceinline__ unsigned int sx32(unsigned int v) {
    return (unsigned int)__shfl_xor((int)v, 32, 64);
}

// Each block: 128 points (4 waves x 32) x s_count subdomains (single chunk of 4
// at ngrp=8). Partial (num, den) per point written to ws.
// MFMA scheme (swapped operands): D = W^T (A, from LDS) x h^T (B, in regs).
__global__ __launch_bounds__(256) void fbpinn_main(
    const float* __restrict__ X,
    const float* __restrict__ centers,
    const float* __restrict__ widths,
    const float* __restrict__ core_min,
    const float* __restrict__ core_max,
    const float* __restrict__ overlap,
    const float* __restrict__ W1,
    const float* __restrict__ b1,
    const float* __restrict__ W2,
    const float* __restrict__ b2,
    const float* __restrict__ W3,
    const float* __restrict__ b3,
    const float* __restrict__ Wout,
    const float* __restrict__ bout,
    float* __restrict__ ws,
    int n_pts, int s_count)
{
    __shared__ __align__(16) unsigned short sW2t[4][1024];  // swizzled [j][k], bf16
    __shared__ __align__(16) unsigned short sW3t[4][1024];
    __shared__ __align__(16) float sW1f[4][64];             // f32 [d][j]
    __shared__ __align__(16) float sB1[4][32], sB2[4][32], sB3[4][32], sWo[4][32];
    __shared__ float sBout[4];
    __shared__ __align__(16) float sWin[4][16];  // window fma coeffs, 64B row (aligned!)

    const int tid  = threadIdx.x;
    const int wave = tid >> 6;
    const int lane = tid & 63;
    const int p    = lane & 31;   // point id within wave; also MFMA D-col
    const int hi   = lane >> 5;   // half selector
    const int s_begin = blockIdx.y * s_count;

    int P = blockIdx.x * 128 + wave * 32 + p;
    if (P >= n_pts) P = n_pts - 1;   // N divides exactly; safety only

    const float t = X[2 * P + 0];
    const float x = X[2 * P + 1];

    float num = 0.0f, den = 0.0f;

    // weight-fragment offsets (A-operand = W^T, row = p as neuron, k-slices)
    const int ef0 = (p << 5) + ((hi * 8)      ^ SWZ(p)); // k 0..15 slice
    const int ef1 = (p << 5) + ((16 + hi * 8) ^ SWZ(p)); // k 16..31 slice

    for (int c0 = 0; c0 < s_count; c0 += 4) {
        __syncthreads();
        // ---- stage 4 subdomains' weights (bf16 W2/W3, f32 W1 + biases) ----
        {
            const float* W2s = W2 + (size_t)(s_begin + c0) * 1024;
            const float* W3s = W3 + (size_t)(s_begin + c0) * 1024;
            #pragma unroll
            for (int i = 0; i < 16; ++i) {
                int e = tid + (i << 8);            // e = sl*1024 + k*32 + j
                int sl = e >> 10, r = e & 1023;
                int k = r >> 5, j = r & 31;
                int di = (j << 5) + (k ^ SWZ(j));  // transposed + swizzle
                sW2t[sl][di] = f2bf(W2s[e]);
                sW3t[sl][di] = f2bf(W3s[e]);
            }
            sW1f[tid >> 6][tid & 63] = W1[(size_t)(s_begin + c0) * 64 + tid];
            if (tid < 128) {
                int sl = tid >> 5, j = tid & 31;
                int g = (s_begin + c0 + sl) * 32 + j;
                sB1[sl][j] = b1[g];
                sB2[sl][j] = b2[g];
                sB3[sl][j] = b3[g];
                sWo[sl][j] = Wout[g];
            }
            if (tid < 4) {
                sBout[tid] = bout[s_begin + c0 + tid];
                int s = s_begin + c0 + tid;     // window coeffs (cold; IEEE div ok)
                #pragma unroll
                for (int d = 0; d < 2; ++d) {
                    float wid = widths[s * 2 + d];
                    float ov  = overlap[s * 2 + d];
                    float sdL = (4.0f / (2.0f * ov * wid + 1e-8f)) * LOG2E;
                    float rw  = 1.0f / wid;
                    // e_left  = exp2(fma(X, -sdL,  sdL*cmin))
                    // e_right = exp2(fma(X,  sdL, -sdL*cmax))
                    sWin[tid][d * 4 + 0] = -sdL;
                    sWin[tid][d * 4 + 1] =  sdL * core_min[s * 2 + d];
                    sWin[tid][d * 4 + 2] =  sdL;
                    sWin[tid][d * 4 + 3] = -sdL * core_max[s * 2 + d];
                    sWin[tid][8 + d]     = rw;
                    sWin[tid][10 + d]    = 0.5f - centers[s * 2 + d] * rw;
                }
            }
        }
        __syncthreads();

        for (int si = 0; si < 4; ++si) {
            // ---- window + normalized coords (aligned f32x4 table reads) ----
            const f32x4* Wn = (const f32x4*)&sWin[si][0];
            f32x4 ca = Wn[0], cb = Wn[1], cc = Wn[2];
            float e0 = exp2_fast(fmaf(t, ca.x, ca.y));   // e^{-z_left,t}
            float e1 = exp2_fast(fmaf(t, ca.z, ca.w));   // e^{-z_right,t}
            float e2 = exp2_fast(fmaf(x, cb.x, cb.y));   // e^{-z_left,x}
            float e3 = exp2_fast(fmaf(x, cb.z, cb.w));   // e^{-z_right,x}
            float w = rcp_fast(((1.0f + e0) * (1.0f + e1)) * ((1.0f + e2) * (1.0f + e3)));
            float xn0 = fmaf(t, cc.x, cc.z);
            float xn1 = fmaf(x, cc.y, cc.w);

            unsigned int pk[8];

            // ---- layer 1 (VALU): lane (p,hi) computes neurons j = 16*hi..+15 ----
            {
                const f32x4* Wa4 = (const f32x4*)&sW1f[si][hi * 16];        // d0
                const f32x4* Wb4 = (const f32x4*)&sW1f[si][32 + hi * 16];   // d1
                const f32x4* Bv4 = (const f32x4*)&sB1[si][hi * 16];
                float Wa[16], Wb[16], Bv[16];
                #pragma unroll
                for (int i = 0; i < 4; ++i) {
                    f32x4 av = Wa4[i], bv = Wb4[i], cv = Bv4[i];
                    #pragma unroll
                    for (int q = 0; q < 4; ++q) {
                        Wa[4 * i + q] = av[q];
                        Wb[4 * i + q] = bv[q];
                        Bv[4 * i + q] = cv[q];
                    }
                }
                #pragma unroll
                for (int q = 0; q < 8; ++q) {
                    float a0 = fmaf(xn0, Wa[2 * q],     fmaf(xn1, Wb[2 * q],     Bv[2 * q]));
                    float a1 = fmaf(xn0, Wa[2 * q + 1], fmaf(xn1, Wb[2 * q + 1], Bv[2 * q + 1]));
                    pk[q] = cvt_pk_bf16(tanh_f(a0), tanh_f(a1));
                }
            }
            // exchange: hi=0 sends j8..15 (pk4..7), hi=1 sends j16..23 (pk0..3)
            bf16x8 Bf0, Bf1;
            {
                unsigned int r0 = sx32(hi ? pk[0] : pk[4]);
                unsigned int r1 = sx32(hi ? pk[1] : pk[5]);
                unsigned int r2 = sx32(hi ? pk[2] : pk[6]);
                unsigned int r3 = sx32(hi ? pk[3] : pk[7]);
                u32x4 f1 = hi ? (u32x4){r0, r1, r2, r3} : (u32x4){pk[0], pk[1], pk[2], pk[3]};
                u32x4 f2 = hi ? (u32x4){pk[4], pk[5], pk[6], pk[7]} : (u32x4){r0, r1, r2, r3};
                Bf0 = __builtin_bit_cast(bf16x8, f1);
                Bf1 = __builtin_bit_cast(bf16x8, f2);
            }

            // ---- layer 2 (MFMA, swapped): D2[j][m] ----
            f32x16 acc;
            {
                bf16x8 A0 = *(bf16x8*)&sW2t[si][ef0];
                bf16x8 A1 = *(bf16x8*)&sW2t[si][ef1];
                #pragma unroll
                for (int i = 0; i < 4; ++i) {
                    f32x4 bv = *(const f32x4*)&sB2[si][8 * i + 4 * hi];
                    #pragma unroll
                    for (int q = 0; q < 4; ++q) acc[4 * i + q] = bv[q];
                }
                acc = __builtin_amdgcn_mfma_f32_32x32x16_bf16(A0, Bf0, acc, 0, 0, 0);
                acc = __builtin_amdgcn_mfma_f32_32x32x16_bf16(A1, Bf1, acc, 0, 0, 0);
            }
            // tanh + pack: pk[q] = neurons (j(2q), j(2q)+1), j(r)=(r&3)+8(r>>2)+4hi
            #pragma unroll
            for (int q = 0; q < 8; ++q)
                pk[q] = cvt_pk_bf16(tanh_f(acc[2 * q]), tanh_f(acc[2 * q + 1]));
            // exchange: hi=0 sends pk2,3 (j8..11) & pk6,7 (j24..27);
            //           hi=1 sends pk0,1 (j4..7)  & pk4,5 (j20..23)
            {
                unsigned int r0 = sx32(hi ? pk[0] : pk[2]);
                unsigned int r1 = sx32(hi ? pk[1] : pk[3]);
                unsigned int r2 = sx32(hi ? pk[4] : pk[6]);
                unsigned int r3 = sx32(hi ? pk[5] : pk[7]);
                u32x4 f1 = hi ? (u32x4){r0, r1, pk[2], pk[3]} : (u32x4){pk[0], pk[1], r0, r1};
                u32x4 f2 = hi ? (u32x4){r2, r3, pk[6], pk[7]} : (u32x4){pk[4], pk[5], r2, r3};
                Bf0 = __builtin_bit_cast(bf16x8, f1);
                Bf1 = __builtin_bit_cast(bf16x8, f2);
            }

            // ---- layer 3 (MFMA, swapped) ----
            {
                bf16x8 A0 = *(bf16x8*)&sW3t[si][ef0];
                bf16x8 A1 = *(bf16x8*)&sW3t[si][ef1];
                #pragma unroll
                for (int i = 0; i < 4; ++i) {
                    f32x4 bv = *(const f32x4*)&sB3[si][8 * i + 4 * hi];
                    #pragma unroll
                    for (int q = 0; q < 4; ++q) acc[4 * i + q] = bv[q];
                }
                acc = __builtin_amdgcn_mfma_f32_32x32x16_bf16(A0, Bf0, acc, 0, 0, 0);
                acc = __builtin_amdgcn_mfma_f32_32x32x16_bf16(A1, Bf1, acc, 0, 0, 0);
            }

            // ---- output dot: y[p] = sum_j tanh(h3[p][j]) * Wout[j] ----
            {
                float yp = 0.0f;
                #pragma unroll
                for (int i = 0; i < 4; ++i) {
                    f32x4 wv = *(const f32x4*)&sWo[si][8 * i + 4 * hi];
                    #pragma unroll
                    for (int q = 0; q < 4; ++q)
                        yp = fmaf(tanh_f(acc[4 * i + q]), wv[q], yp);
                }
                float y = yp + __shfl_xor(yp, 32, 64);   // combine both halves
                y += sBout[si];
                num = fmaf(w, y, num);
                den += w;
            }
        }
    }

    if (hi == 0) {
        const int grp = blockIdx.y;
        ws[(size_t)(2 * grp)     * n_pts + P] = num;
        ws[(size_t)(2 * grp + 1) * n_pts + P] = den;
    }
}

// normalize + scale/shift + ansatz epilogue
__global__ __launch_bounds__(256) void fbpinn_combine(
    const float* __restrict__ X,
    const float* __restrict__ scale,
    const float* __restrict__ shift,
    const float* __restrict__ ws,
    float* __restrict__ out,
    int n_pts, int ngrp)
{
    const int P = blockIdx.x * 256 + threadIdx.x;
    if (P >= n_pts) return;
    float num = 0.0f, den = 0.0f;
    for (int g = 0; g < ngrp; ++g) {
        num += ws[(size_t)(2 * g)     * n_pts + P];
        den += ws[(size_t)(2 * g + 1) * n_pts + P];
    }
    // scale/shift are affine in y: sum w*(sc*y+sh) = sc*sum(w*y) + sh*sum(w)
    const float sc = scale[0], sh = shift[0];
    float u = fmaf(sc, num, sh * den) / (den + 1e-8f);
    const float t = X[2 * P + 0];
    const float x = X[2 * P + 1];
    float fac = tanh_f(x + 1.0f) * tanh_f(x - 1.0f) * tanh_f(t);
    const float pi = 3.14159265358979323846f;
    out[P] = fmaf(fac, u, -__sinf(pi * x));
}

extern "C" void kernel_launch(void* const* d_in, const int* in_sizes, int n_in,
                              void* d_out, int out_size, void* d_ws, size_t ws_size,
                              hipStream_t stream) {
    const float* X        = (const float*)d_in[0];
    const float* centers  = (const float*)d_in[1];
    const float* widths   = (const float*)d_in[2];
    const float* core_min = (const float*)d_in[3];
    const float* core_max = (const float*)d_in[4];
    const float* overlap  = (const float*)d_in[5];
    const float* W1       = (const float*)d_in[6];
    const float* b1       = (const float*)d_in[7];
    const float* W2       = (const float*)d_in[8];
    const float* b2       = (const float*)d_in[9];
    const float* W3       = (const float*)d_in[10];
    const float* b3       = (const float*)d_in[11];
    const float* Wout     = (const float*)d_in[12];
    const float* bout     = (const float*)d_in[13];
    const float* scale    = (const float*)d_in[14];
    const float* shift    = (const float*)d_in[15];

    float* out = (float*)d_out;
    float* ws  = (float*)d_ws;
    const int n_pts = in_sizes[0] / 2;

    int ngrp = 8;
    while (ngrp > 1 && (size_t)2 * ngrp * n_pts * sizeof(float) > ws_size) ngrp >>= 1;
    const int s_count = 32 / ngrp;

    dim3 grid((n_pts + 127) / 128, ngrp);
    fbpinn_main<<<grid, 256, 0, stream>>>(
        X, centers, widths, core_min, core_max, overlap,
        W1, b1, W2, b2, W3, b3, Wout, bout,
        ws, n_pts, s_count);

    fbpinn_combine<<<(n_pts + 255) / 256, 256, 0, stream>>>(
        X, scale, shift, ws, out, n_pts, ngrp);
}

// Round 14
// 199.788 us; speedup vs baseline: 1.1539x; 1.0367x over previous
//
#include <hip/hip_runtime.h>
#include <math.h>

typedef short    bf16x8 __attribute__((ext_vector_type(8)));
typedef float    f32x16 __attribute__((ext_vector_type(16)));
typedef float    f32x4  __attribute__((ext_vector_type(4)));
typedef float    f32x2  __attribute__((ext_vector_type(2)));
typedef unsigned int u32x4 __attribute__((ext_vector_type(4)));

// element-granular XOR swizzle for the weight tiles (64B-stride rows -> all banks)
#define SWZ(row) ((((row) >> 1) & 3) << 3)

__device__ __forceinline__ unsigned short f2bf(float f) {
    unsigned int u = __builtin_bit_cast(unsigned int, f);
    u = (u + 0x7FFFu + ((u >> 16) & 1u)) >> 16;   // RNE
    return (unsigned short)u;
}
__device__ __forceinline__ unsigned int cvt_pk_bf16(float lo, float hi) {
    unsigned int r;
    asm("v_cvt_pk_bf16_f32 %0, %1, %2" : "=v"(r) : "v"(lo), "v"(hi));
    return r;   // RNE
}
__device__ __forceinline__ float rcp_fast(float x) { return __builtin_amdgcn_rcpf(x); }

__device__ __forceinline__ float exp2_fast(float x) {
    float r; asm("v_exp_f32 %0, %1" : "=v"(r) : "v"(x)); return r;
}
// packed f32 VOP3P ops (gfx90a+); IEEE-identical to scalar
__device__ __forceinline__ f32x2 pk_mul(f32x2 a, f32x2 b) {
    f32x2 d; asm("v_pk_mul_f32 %0, %1, %2" : "=v"(d) : "v"(a), "v"(b)); return d;
}
__device__ __forceinline__ f32x2 pk_add(f32x2 a, f32x2 b) {
    f32x2 d; asm("v_pk_add_f32 %0, %1, %2" : "=v"(d) : "v"(a), "v"(b)); return d;
}
__device__ __forceinline__ f32x2 pk_fma(f32x2 a, f32x2 b, f32x2 c) {
    f32x2 d; asm("v_pk_fma_f32 %0, %1, %2, %3" : "=v"(d) : "v"(a), "v"(b), "v"(c)); return d;
}

#define TWO_LOG2E 2.8853900817779268f   // 2*log2(e)
#define LOG2E     1.4426950408889634f

// tanh(z) = 1 - 2/(2^(z*2log2e)+1); scalar form (window / epilogue)
__device__ __forceinline__ float tanh_f(float z) {
    return fmaf(-2.0f, rcp_fast(exp2_fast(z * TWO_LOG2E) + 1.0f), 1.0f);
}
// packed pair tanh -> f32x2
__device__ __forceinline__ f32x2 tanh2(f32x2 z) {
    f32x2 u = pk_mul(z, (f32x2){TWO_LOG2E, TWO_LOG2E});
    f32x2 e = { exp2_fast(u.x), exp2_fast(u.y) };
    f32x2 ep = pk_add(e, (f32x2){1.0f, 1.0f});
    f32x2 r = { rcp_fast(ep.x), rcp_fast(ep.y) };
    return pk_fma(r, (f32x2){-2.0f, -2.0f}, (f32x2){1.0f, 1.0f});
}
// packed pair tanh -> packed bf16 pair
__device__ __forceinline__ unsigned int tanh_pair_pk(f32x2 z) {
    f32x2 th = tanh2(z);
    return cvt_pk_bf16(th.x, th.y);
}
__device__ __forceinline__ unsigned int sx32(unsigned int v) {
    return (unsigned int)__shfl_xor((int)v, 32, 64);
}

// Each block: 128 points (4 waves x 32) x s_count subdomains. Partial (num, den)
// per point written to ws. MFMA swapped operands: D = W^T x h^T; activations in regs.
__global__ __launch_bounds__(256) void fbpinn_main(
    const float* __restrict__ X,
    const float* __restrict__ centers,
    const float* __restrict__ widths,
    const float* __restrict__ core_min,
    const float* __restrict__ core_max,
    const float* __restrict__ overlap,
    const float* __restrict__ W1,
    const float* __restrict__ b1,
    const float* __restrict__ W2,
    const float* __restrict__ b2,
    const float* __restrict__ W3,
    const float* __restrict__ b3,
    const float* __restrict__ Wout,
    const float* __restrict__ bout,
    float* __restrict__ ws,
    int n_pts, int s_count)
{
    __shared__ __align__(16) unsigned short sW2t[4][1024];  // swizzled [j][k], bf16
    __shared__ __align__(16) unsigned short sW3t[4][1024];
    __shared__ __align__(16) float sW1f[4][64];             // f32 [d][j]
    __shared__ __align__(16) float sB1[4][32], sB2[4][32], sB3[4][32], sWo[4][32];
    __shared__ float sBout[4];
    __shared__ __align__(16) float sWin[4][16];  // window fma coeffs, 64B row (aligned)

    const int tid  = threadIdx.x;
    const int wave = tid >> 6;
    const int lane = tid & 63;
    const int p    = lane & 31;   // point id within wave; also MFMA D-col
    const int hi   = lane >> 5;   // half selector
    const int s_begin = blockIdx.y * s_count;

    int P = blockIdx.x * 128 + wave * 32 + p;
    if (P >= n_pts) P = n_pts - 1;   // N divides exactly; safety only

    const float t = X[2 * P + 0];
    const float x = X[2 * P + 1];

    float num = 0.0f, den = 0.0f;

    // weight-fragment offsets (A-operand = W^T, row = p as neuron, k-slices)
    const int ef0 = (p << 5) + ((hi * 8)      ^ SWZ(p)); // k 0..15 slice
    const int ef1 = (p << 5) + ((16 + hi * 8) ^ SWZ(p)); // k 16..31 slice

    for (int c0 = 0; c0 < s_count; c0 += 4) {
        __syncthreads();
        // ---- stage 4 subdomains' weights (bf16 W2/W3, f32 W1 + biases) ----
        {
            const float* W2s = W2 + (size_t)(s_begin + c0) * 1024;
            const float* W3s = W3 + (size_t)(s_begin + c0) * 1024;
            #pragma unroll
            for (int i = 0; i < 16; ++i) {
                int e = tid + (i << 8);            // e = sl*1024 + k*32 + j
                int sl = e >> 10, r = e & 1023;
                int k = r >> 5, j = r & 31;
                int di = (j << 5) + (k ^ SWZ(j));  // transposed + swizzle
                sW2t[sl][di] = f2bf(W2s[e]);
                sW3t[sl][di] = f2bf(W3s[e]);
            }
            sW1f[tid >> 6][tid & 63] = W1[(size_t)(s_begin + c0) * 64 + tid];
            if (tid < 128) {
                int sl = tid >> 5, j = tid & 31;
                int g = (s_begin + c0 + sl) * 32 + j;
                sB1[sl][j] = b1[g];
                sB2[sl][j] = b2[g];
                sB3[sl][j] = b3[g];
                sWo[sl][j] = Wout[g];
            }
            if (tid < 4) {
                sBout[tid] = bout[s_begin + c0 + tid];
                int s = s_begin + c0 + tid;     // window coeffs (cold; IEEE div ok)
                #pragma unroll
                for (int d = 0; d < 2; ++d) {
                    float wid = widths[s * 2 + d];
                    float ov  = overlap[s * 2 + d];
                    float sdL = (4.0f / (2.0f * ov * wid + 1e-8f)) * LOG2E;
                    float rw  = 1.0f / wid;
                    sWin[tid][d * 4 + 0] = -sdL;
                    sWin[tid][d * 4 + 1] =  sdL * core_min[s * 2 + d];
                    sWin[tid][d * 4 + 2] =  sdL;
                    sWin[tid][d * 4 + 3] = -sdL * core_max[s * 2 + d];
                    sWin[tid][8 + d]     = rw;
                    sWin[tid][10 + d]    = 0.5f - centers[s * 2 + d] * rw;
                }
            }
        }
        __syncthreads();

        for (int si = 0; si < 4; ++si) {
            // ---- window + normalized coords (aligned f32x4 table reads) ----
            const f32x4* Wn = (const f32x4*)&sWin[si][0];
            f32x4 ca = Wn[0], cb = Wn[1], cc = Wn[2];
            float e0 = exp2_fast(fmaf(t, ca.x, ca.y));
            float e1 = exp2_fast(fmaf(t, ca.z, ca.w));
            float e2 = exp2_fast(fmaf(x, cb.x, cb.y));
            float e3 = exp2_fast(fmaf(x, cb.z, cb.w));
            float w = rcp_fast(((1.0f + e0) * (1.0f + e1)) * ((1.0f + e2) * (1.0f + e3)));
            float xn0 = fmaf(t, cc.x, cc.z);
            float xn1 = fmaf(x, cc.y, cc.w);
            const f32x2 xn0v = {xn0, xn0};
            const f32x2 xn1v = {xn1, xn1};

            unsigned int pk[8];

            // ---- layer 1 (VALU, packed): neurons j = 16*hi + 0..15 ----
            {
                const f32x4* Wa4 = (const f32x4*)&sW1f[si][hi * 16];        // d0
                const f32x4* Wb4 = (const f32x4*)&sW1f[si][32 + hi * 16];   // d1
                const f32x4* Bv4 = (const f32x4*)&sB1[si][hi * 16];
                f32x2 WA[8], WB[8], BV[8];
                #pragma unroll
                for (int i = 0; i < 4; ++i) {
                    f32x4 av = Wa4[i], bv = Wb4[i], cv = Bv4[i];
                    WA[2 * i] = av.xy; WA[2 * i + 1] = av.zw;
                    WB[2 * i] = bv.xy; WB[2 * i + 1] = bv.zw;
                    BV[2 * i] = cv.xy; BV[2 * i + 1] = cv.zw;
                }
                #pragma unroll
                for (int q = 0; q < 8; ++q) {
                    f32x2 a = pk_fma(xn0v, WA[q], pk_fma(xn1v, WB[q], BV[q]));
                    pk[q] = tanh_pair_pk(a);
                }
            }
            // exchange: hi=0 sends j8..15 (pk4..7), hi=1 sends j16..23 (pk0..3)
            bf16x8 Bf0, Bf1;
            {
                unsigned int r0 = sx32(hi ? pk[0] : pk[4]);
                unsigned int r1 = sx32(hi ? pk[1] : pk[5]);
                unsigned int r2 = sx32(hi ? pk[2] : pk[6]);
                unsigned int r3 = sx32(hi ? pk[3] : pk[7]);
                u32x4 f1 = hi ? (u32x4){r0, r1, r2, r3} : (u32x4){pk[0], pk[1], pk[2], pk[3]};
                u32x4 f2 = hi ? (u32x4){pk[4], pk[5], pk[6], pk[7]} : (u32x4){r0, r1, r2, r3};
                Bf0 = __builtin_bit_cast(bf16x8, f1);
                Bf1 = __builtin_bit_cast(bf16x8, f2);
            }

            // ---- layer 2 (MFMA, swapped): D2[j][m] ----
            f32x16 acc;
            {
                bf16x8 A0 = *(bf16x8*)&sW2t[si][ef0];
                bf16x8 A1 = *(bf16x8*)&sW2t[si][ef1];
                #pragma unroll
                for (int i = 0; i < 4; ++i) {
                    f32x4 bv = *(const f32x4*)&sB2[si][8 * i + 4 * hi];
                    #pragma unroll
                    for (int q = 0; q < 4; ++q) acc[4 * i + q] = bv[q];
                }
                acc = __builtin_amdgcn_mfma_f32_32x32x16_bf16(A0, Bf0, acc, 0, 0, 0);
                acc = __builtin_amdgcn_mfma_f32_32x32x16_bf16(A1, Bf1, acc, 0, 0, 0);
            }
            // tanh + pack (packed): pk[q] = neurons (j(2q), j(2q)+1)
            #pragma unroll
            for (int q = 0; q < 8; ++q)
                pk[q] = tanh_pair_pk((f32x2){acc[2 * q], acc[2 * q + 1]});
            // exchange: hi=0 sends pk2,3 & pk6,7; hi=1 sends pk0,1 & pk4,5
            {
                unsigned int r0 = sx32(hi ? pk[0] : pk[2]);
                unsigned int r1 = sx32(hi ? pk[1] : pk[3]);
                unsigned int r2 = sx32(hi ? pk[4] : pk[6]);
                unsigned int r3 = sx32(hi ? pk[5] : pk[7]);
                u32x4 f1 = hi ? (u32x4){r0, r1, pk[2], pk[3]} : (u32x4){pk[0], pk[1], r0, r1};
                u32x4 f2 = hi ? (u32x4){r2, r3, pk[6], pk[7]} : (u32x4){pk[4], pk[5], r2, r3};
                Bf0 = __builtin_bit_cast(bf16x8, f1);
                Bf1 = __builtin_bit_cast(bf16x8, f2);
            }

            // ---- layer 3 (MFMA, swapped) ----
            {
                bf16x8 A0 = *(bf16x8*)&sW3t[si][ef0];
                bf16x8 A1 = *(bf16x8*)&sW3t[si][ef1];
                #pragma unroll
                for (int i = 0; i < 4; ++i) {
                    f32x4 bv = *(const f32x4*)&sB3[si][8 * i + 4 * hi];
                    #pragma unroll
                    for (int q = 0; q < 4; ++q) acc[4 * i + q] = bv[q];
                }
                acc = __builtin_amdgcn_mfma_f32_32x32x16_bf16(A0, Bf0, acc, 0, 0, 0);
                acc = __builtin_amdgcn_mfma_f32_32x32x16_bf16(A1, Bf1, acc, 0, 0, 0);
            }

            // ---- output dot (packed): y[p] = sum_j tanh(h3[p][j]) * Wout[j] ----
            {
                f32x2 acc2 = {0.0f, 0.0f};
                #pragma unroll
                for (int i = 0; i < 4; ++i) {
                    f32x4 wv = *(const f32x4*)&sWo[si][8 * i + 4 * hi];
                    f32x2 th0 = tanh2((f32x2){acc[4 * i + 0], acc[4 * i + 1]});
                    f32x2 th1 = tanh2((f32x2){acc[4 * i + 2], acc[4 * i + 3]});
                    acc2 = pk_fma(th0, wv.xy, acc2);
                    acc2 = pk_fma(th1, wv.zw, acc2);
                }
                float yp = acc2.x + acc2.y;
                float y = yp + __shfl_xor(yp, 32, 64);   // combine both halves
                y += sBout[si];
                num = fmaf(w, y, num);
                den += w;
            }
        }
    }

    if (hi == 0) {
        const int grp = blockIdx.y;
        ws[(size_t)(2 * grp)     * n_pts + P] = num;
        ws[(size_t)(2 * grp + 1) * n_pts + P] = den;
    }
}

// normalize + scale/shift + ansatz epilogue
__global__ __launch_bounds__(256) void fbpinn_combine(
    const float* __restrict__ X,
    const float* __restrict__ scale,
    const float* __restrict__ shift,
    const float* __restrict__ ws,
    float* __restrict__ out,
    int n_pts, int ngrp)
{
    const int P = blockIdx.x * 256 + threadIdx.x;
    if (P >= n_pts) return;
    float num = 0.0f, den = 0.0f;
    for (int g = 0; g < ngrp; ++g) {
        num += ws[(size_t)(2 * g)     * n_pts + P];
        den += ws[(size_t)(2 * g + 1) * n_pts + P];
    }
    // scale/shift are affine in y: sum w*(sc*y+sh) = sc*sum(w*y) + sh*sum(w)
    const float sc = scale[0], sh = shift[0];
    float u = fmaf(sc, num, sh * den) / (den + 1e-8f);
    const float t = X[2 * P + 0];
    const float x = X[2 * P + 1];
    float fac = tanh_f(x + 1.0f) * tanh_f(x - 1.0f) * tanh_f(t);
    const float pi = 3.14159265358979323846f;
    out[P] = fmaf(fac, u, -__sinf(pi * x));
}

extern "C" void kernel_launch(void* const* d_in, const int* in_sizes, int n_in,
                              void* d_out, int out_size, void* d_ws, size_t ws_size,
                              hipStream_t stream) {
    const float* X        = (const float*)d_in[0];
    const float* centers  = (const float*)d_in[1];
    const float* widths   = (const float*)d_in[2];
    const float* core_min = (const float*)d_in[3];
    const float* core_max = (const float*)d_in[4];
    const float* overlap  = (const float*)d_in[5];
    const float* W1       = (const float*)d_in[6];
    const float* b1       = (const float*)d_in[7];
    const float* W2       = (const float*)d_in[8];
    const float* b2       = (const float*)d_in[9];
    const float* W3       = (const float*)d_in[10];
    const float* b3       = (const float*)d_in[11];
    const float* Wout     = (const float*)d_in[12];
    const float* bout     = (const float*)d_in[13];
    const float* scale    = (const float*)d_in[14];
    const float* shift    = (const float*)d_in[15];

    float* out = (float*)d_out;
    float* ws  = (float*)d_ws;
    const int n_pts = in_sizes[0] / 2;

    int ngrp = 8;
    while (ngrp > 1 && (size_t)2 * ngrp * n_pts * sizeof(float) > ws_size) ngrp >>= 1;
    const int s_count = 32 / ngrp;

    dim3 grid((n_pts + 127) / 128, ngrp);
    fbpinn_main<<<grid, 256, 0, stream>>>(
        X, centers, widths, core_min, core_max, overlap,
        W1, b1, W2, b2, W3, b3, Wout, bout,
        ws, n_pts, s_count);

    fbpinn_combine<<<(n_pts + 255) / 256, 256, 0, stream>>>(
        X, scale, shift, ws, out, n_pts, ngrp);
}